// Round 1
// baseline (1288.887 us; speedup 1.0000x reference)
//
#include <hip/hip_runtime.h>
#include <math.h>

#define HW 2304      // 48*48
#define NC 256       // channels
#define NPIX 2500    // 50*50 padded
#define MATSZ 65536  // 256*256
#define NS_ITERS 10

typedef unsigned long long u64;

// ---------------- reduction helper (block of 256) ----------------
__device__ __forceinline__ double blockReduceSum256(double v, double* sd) {
  int t = threadIdx.x;
  sd[t] = v; __syncthreads();
  for (int s = 128; s > 0; s >>= 1) {
    if (t < s) sd[t] += sd[t + s];
    __syncthreads();
  }
  return sd[0];
}

// ---------------- means (f64) ----------------
// grid(256, 4), block(64). mat 0,1 = c batches; mat 2,3 = s batches.
__global__ void mean_kernel(const float* __restrict__ c, const float* __restrict__ s,
                            double* __restrict__ mean) {
  int ch = blockIdx.x, m = blockIdx.y;
  const float* src = (m < 2 ? c + m * (NC * HW) : s + (m - 2) * (NC * HW)) + ch * HW;
  double acc = 0.0;
  for (int n = threadIdx.x; n < HW; n += 64) acc += (double)src[n];
  for (int o = 32; o > 0; o >>= 1) acc += __shfl_down(acc, o);
  if (threadIdx.x == 0) mean[m * NC + ch] = acc / (double)HW;
}

// ---------------- covariance (f64 accum -> f32) ----------------
// grid(16,16,4), block(16,16)
__launch_bounds__(256)
__global__ void cov_kernel(const float* __restrict__ c, const float* __restrict__ s,
                           const double* __restrict__ mean, float* __restrict__ cov) {
  int m = blockIdx.z;
  const float* src = (m < 2 ? c + m * (NC * HW) : s + (m - 2) * (NC * HW));
  int i0 = blockIdx.y * 16, j0 = blockIdx.x * 16;
  __shared__ float a[16][129], b[16][129];
  int tx = threadIdx.x, ty = threadIdx.y;
  int tid = ty * 16 + tx;
  double mi = mean[m * NC + i0 + ty];
  double mj = mean[m * NC + j0 + tx];
  double acc = 0.0;
  for (int n0 = 0; n0 < HW; n0 += 128) {
    __syncthreads();
    #pragma unroll
    for (int l = 0; l < 8; ++l) {
      int idx = tid + l * 256;
      int r = idx >> 7, col = idx & 127;
      a[r][col] = src[(i0 + r) * HW + n0 + col];
      b[r][col] = src[(j0 + r) * HW + n0 + col];
    }
    __syncthreads();
    for (int n = 0; n < 128; ++n)
      acc += ((double)a[ty][n] - mi) * ((double)b[tx][n] - mj);
  }
  cov[m * MATSZ + (i0 + ty) * NC + j0 + tx] = (float)acc;
}

// ---------------- trace -> NS scale ----------------
// grid(4), block(256). s = 1.25 * trace/256 puts spectrum in ~[0.36,1.43] (<2: NS basin)
__global__ void trace_kernel(const float* __restrict__ cov, double* __restrict__ snorm) {
  int m = blockIdx.x, t = threadIdx.x;
  __shared__ double sd[256];
  double v = (double)cov[m * MATSZ + t * 257];
  double tr = blockReduceSum256(v, sd);
  if (t == 0) snorm[m] = 1.25 * tr / 256.0;
}

// grid(256,4), block(256)
__global__ void ns_init(const float* __restrict__ cov, const double* __restrict__ snorm,
                        float* __restrict__ Y, float* __restrict__ Z) {
  int m = blockIdx.y;
  int e = blockIdx.x * 256 + threadIdx.x;
  double inv = 1.0 / snorm[m];
  Y[m * MATSZ + e] = (float)((double)cov[m * MATSZ + e] * inv);
  Z[m * MATSZ + e] = ((e >> 8) == (e & 255)) ? 1.0f : 0.0f;
}

// ---------------- Newton-Schulz GEMMs (256x256x256, f32) ----------------
// T = 1.5 I - 0.5 * Z * Y     grid(8,8,4), block(16,16), 32x32 tile
__launch_bounds__(256)
__global__ void ns_gemm_T(const float* __restrict__ Zc, const float* __restrict__ Yc,
                          float* __restrict__ T) {
  int m = blockIdx.z;
  const float* A = Zc + m * MATSZ;
  const float* B = Yc + m * MATSZ;
  int m0 = blockIdx.y * 32, n0 = blockIdx.x * 32;
  __shared__ float As[32][33], Bs[32][33];
  int tx = threadIdx.x, ty = threadIdx.y;
  int tid = ty * 16 + tx;
  float acc[2][2] = {};
  for (int k0 = 0; k0 < 256; k0 += 32) {
    __syncthreads();
    #pragma unroll
    for (int l = 0; l < 4; ++l) {
      int idx = tid + l * 256;
      int r = idx >> 5, cc = idx & 31;
      As[r][cc] = A[(m0 + r) * NC + k0 + cc];
      Bs[r][cc] = B[(k0 + r) * NC + n0 + cc];
    }
    __syncthreads();
    #pragma unroll
    for (int kk = 0; kk < 32; ++kk) {
      float a0 = As[ty][kk], a1 = As[ty + 16][kk];
      float b0 = Bs[kk][tx], b1 = Bs[kk][tx + 16];
      acc[0][0] += a0 * b0; acc[0][1] += a0 * b1;
      acc[1][0] += a1 * b0; acc[1][1] += a1 * b1;
    }
  }
  float* Cp = T + m * MATSZ;
  #pragma unroll
  for (int i = 0; i < 2; ++i)
    #pragma unroll
    for (int j = 0; j < 2; ++j) {
      int row = m0 + ty + 16 * i, col = n0 + tx + 16 * j;
      Cp[row * NC + col] = (row == col ? 1.5f : 0.0f) - 0.5f * acc[i][j];
    }
}

// z<4: Yn = Yc*T ; z>=4: Zn = T*Zc   grid(8,8,8), block(16,16)
__launch_bounds__(256)
__global__ void ns_gemm_YZ(const float* __restrict__ Yc, const float* __restrict__ Zc,
                           const float* __restrict__ T,
                           float* __restrict__ Yn, float* __restrict__ Zn) {
  int z = blockIdx.z;
  int m = z & 3;
  bool isY = (z < 4);
  const float* A = isY ? (Yc + m * MATSZ) : (T + m * MATSZ);
  const float* B = isY ? (T + m * MATSZ) : (Zc + m * MATSZ);
  float* Cp = isY ? (Yn + m * MATSZ) : (Zn + m * MATSZ);
  int m0 = blockIdx.y * 32, n0 = blockIdx.x * 32;
  __shared__ float As[32][33], Bs[32][33];
  int tx = threadIdx.x, ty = threadIdx.y;
  int tid = ty * 16 + tx;
  float acc[2][2] = {};
  for (int k0 = 0; k0 < 256; k0 += 32) {
    __syncthreads();
    #pragma unroll
    for (int l = 0; l < 4; ++l) {
      int idx = tid + l * 256;
      int r = idx >> 5, cc = idx & 31;
      As[r][cc] = A[(m0 + r) * NC + k0 + cc];
      Bs[r][cc] = B[(k0 + r) * NC + n0 + cc];
    }
    __syncthreads();
    #pragma unroll
    for (int kk = 0; kk < 32; ++kk) {
      float a0 = As[ty][kk], a1 = As[ty + 16][kk];
      float b0 = Bs[kk][tx], b1 = Bs[kk][tx + 16];
      acc[0][0] += a0 * b0; acc[0][1] += a0 * b1;
      acc[1][0] += a1 * b0; acc[1][1] += a1 * b1;
    }
  }
  #pragma unroll
  for (int i = 0; i < 2; ++i)
    #pragma unroll
    for (int j = 0; j < 2; ++j)
      Cp[(m0 + ty + 16 * i) * NC + n0 + tx + 16 * j] = acc[i][j];
}

// ---------------- whitening apply -> padded norm buffers ----------------
// norm = (1/sqrt(s)) * Zf * (x - mean). grid(36,8,4), block(16,16): 32 ch x 64 n tile.
__launch_bounds__(256)
__global__ void whiten_kernel(const float* __restrict__ c, const float* __restrict__ s,
                              const float* __restrict__ Zf,
                              const double* __restrict__ snorm, const double* __restrict__ mean,
                              float* __restrict__ padC_cf, float* __restrict__ padS_cf,
                              float* __restrict__ padS_cl) {
  int mat = blockIdx.z;
  const float* src = (mat < 2 ? c + mat * (NC * HW) : s + (mat - 2) * (NC * HW));
  const float* A = Zf + mat * MATSZ;
  const double* mn = mean + mat * NC;
  float wscale = (float)(1.0 / sqrt(snorm[mat]));
  int m0 = blockIdx.y * 32, n0 = blockIdx.x * 64;
  __shared__ float As[32][33];
  __shared__ float Bs[32][65];
  int tx = threadIdx.x, ty = threadIdx.y;
  int tid = ty * 16 + tx;
  float acc[2][4] = {};
  for (int k0 = 0; k0 < 256; k0 += 32) {
    __syncthreads();
    #pragma unroll
    for (int l = 0; l < 4; ++l) {
      int idx = tid + l * 256;
      int r = idx >> 5, cc = idx & 31;
      As[r][cc] = A[(m0 + r) * NC + k0 + cc];
    }
    #pragma unroll
    for (int l = 0; l < 8; ++l) {
      int idx = tid + l * 256;
      int kk = idx >> 6, nn = idx & 63;
      Bs[kk][nn] = src[(k0 + kk) * HW + n0 + nn] - (float)mn[k0 + kk];
    }
    __syncthreads();
    #pragma unroll
    for (int kk = 0; kk < 32; ++kk) {
      float a0 = As[ty][kk], a1 = As[ty + 16][kk];
      float b0 = Bs[kk][tx], b1 = Bs[kk][tx + 16], b2 = Bs[kk][tx + 32], b3 = Bs[kk][tx + 48];
      acc[0][0] += a0 * b0; acc[0][1] += a0 * b1; acc[0][2] += a0 * b2; acc[0][3] += a0 * b3;
      acc[1][0] += a1 * b0; acc[1][1] += a1 * b1; acc[1][2] += a1 * b2; acc[1][3] += a1 * b3;
    }
  }
  #pragma unroll
  for (int i = 0; i < 2; ++i) {
    int row = m0 + ty + 16 * i;
    #pragma unroll
    for (int j = 0; j < 4; ++j) {
      int n = n0 + tx + 16 * j;
      float v = acc[i][j] * wscale;
      int y = n / 48, x = n % 48;
      int ppos = (y + 1) * 50 + (x + 1);
      if (mat < 2) {
        padC_cf[mat * (NC * NPIX) + row * NPIX + ppos] = v;
      } else {
        padS_cf[(mat - 2) * (NC * NPIX) + row * NPIX + ppos] = v;
        padS_cl[(mat - 2) * (NPIX * NC) + ppos * NC + row] = v;
      }
    }
  }
}

// ---------------- patch norms: rknorm = 1/||ker(ps)|| ----------------
// grid(2304,2), block(256)=channels
__global__ void knorm_kernel(const float* __restrict__ padS_cl, float* __restrict__ rknorm) {
  int ps = blockIdx.x, b = blockIdx.y;
  int ys = ps / 48, xs = ps % 48;
  const float* S = padS_cl + b * (NPIX * NC);
  int ch = threadIdx.x;
  double acc = 0.0;
  #pragma unroll
  for (int dy = 0; dy < 3; ++dy)
    #pragma unroll
    for (int dx = 0; dx < 3; ++dx) {
      float v = S[((ys + dy) * 50 + xs + dx) * NC + ch];
      acc += (double)v * (double)v;
    }
  __shared__ double sd[256];
  double tot = blockReduceSum256(acc, sd);
  if (ch == 0) rknorm[b * HW + ps] = (float)(1.0 / sqrt(tot));
}

// ---------------- score GEMM: scores[pc][ps] = <patch_c(pc), ker_s(ps)> ----------------
// K ordered as (r=dy*3+dx, ch): per 16-chunk r is constant. grid(36,36), block(16,16), 64x64 tile.
__launch_bounds__(256)
__global__ void score_gemm(const float* __restrict__ padC_cf, const float* __restrict__ padS_cf,
                           float* __restrict__ scores, int b) {
  const float* A = padC_cf + b * (NC * NPIX);
  const float* B = padS_cf + b * (NC * NPIX);
  int m0 = blockIdx.x * 64, n0 = blockIdx.y * 64;
  __shared__ float As[16][64], Bs[16][64];
  int tx = threadIdx.x, ty = threadIdx.y;
  int tid = ty * 16 + tx;
  int mm = tid & 63;
  int kb = tid >> 6;  // 0..3
  int am = m0 + mm; int apos = (am / 48) * 50 + (am % 48);
  int bn = n0 + mm; int bpos = (bn / 48) * 50 + (bn % 48);
  float acc[4][4] = {};
  for (int r = 0; r < 9; ++r) {
    int off = (r / 3) * 50 + (r % 3);
    const float* Ar = A + apos + off;
    const float* Br = B + bpos + off;
    for (int c0 = 0; c0 < 256; c0 += 16) {
      __syncthreads();
      #pragma unroll
      for (int l = 0; l < 4; ++l) {
        int kk = kb * 4 + l;
        As[kk][mm] = Ar[(c0 + kk) * NPIX];
        Bs[kk][mm] = Br[(c0 + kk) * NPIX];
      }
      __syncthreads();
      #pragma unroll
      for (int kk = 0; kk < 16; ++kk) {
        float4 av = *(const float4*)&As[kk][ty * 4];
        float4 bv = *(const float4*)&Bs[kk][tx * 4];
        float a4[4] = {av.x, av.y, av.z, av.w};
        float b4[4] = {bv.x, bv.y, bv.z, bv.w};
        #pragma unroll
        for (int i = 0; i < 4; ++i)
          #pragma unroll
          for (int j = 0; j < 4; ++j) acc[i][j] += a4[i] * b4[j];
      }
    }
  }
  #pragma unroll
  for (int i = 0; i < 4; ++i) {
    int row = m0 + ty * 4 + i;
    float4 v = make_float4(acc[i][0], acc[i][1], acc[i][2], acc[i][3]);
    *(float4*)&scores[row * HW + n0 + tx * 4] = v;
  }
}

// ---------------- argmax over ps (first-max tie-break) ----------------
// grid(2304), block(256); scores holds one batch
__global__ void argmax_kernel(const float* __restrict__ scores, const float* __restrict__ rknorm,
                              int* __restrict__ ridx, int b) {
  int pc = blockIdx.x;
  const float* row = scores + (u64)pc * HW;
  const float* rk = rknorm + b * HW;
  int t = threadIdx.x;
  float best = -1e30f; int bi = 0;
  for (int ps = t; ps < HW; ps += 256) {
    float v = row[ps] * rk[ps];
    if (v > best) { best = v; bi = ps; }   // strict >: keeps smallest ps within thread
  }
  __shared__ float sv[256]; __shared__ int si[256];
  sv[t] = best; si[t] = bi; __syncthreads();
  for (int s = 128; s > 0; s >>= 1) {
    if (t < s) {
      if (sv[t + s] > sv[t] || (sv[t + s] == sv[t] && si[t + s] < si[t])) {
        sv[t] = sv[t + s]; si[t] = si[t + s];
      }
    }
    __syncthreads();
  }
  if (t == 0) ridx[b * HW + pc] = si[0];
}

// ---------------- reassemble: paste chosen patches + overlap normalize ----------------
// rF[c,y,x] = sum_{i,j} ker[idx[y+1-i, x+1-j], c, i, j] / (cnt_y*cnt_x)
// grid(2304,2), block(256)=channels. Output channel-last rF_cl[b][pix][ch].
__global__ void reassemble_kernel(const float* __restrict__ padS_cl, const int* __restrict__ ridx,
                                  float* __restrict__ rF_cl) {
  int pix = blockIdx.x, b = blockIdx.y;
  int y = pix / 48, x = pix % 48;
  const int* idx = ridx + b * HW;
  const float* S = padS_cl + b * (NPIX * NC);
  int ch = threadIdx.x;
  float sum = 0.0f;
  #pragma unroll
  for (int i = 0; i < 3; ++i)
    #pragma unroll
    for (int j = 0; j < 3; ++j) {
      int yn = y + 1 - i, xn = x + 1 - j;
      if (yn >= 0 && yn < 48 && xn >= 0 && xn < 48) {
        int ps = idx[yn * 48 + xn];
        int ys = ps / 48, xs = ps % 48;
        sum += S[((ys + i) * 50 + xs + j) * NC + ch];
      }
    }
  float cy = (y == 0 || y == 47) ? 2.0f : 3.0f;
  float cx = (x == 0 || x == 47) ? 2.0f : 3.0f;
  rF_cl[b * (HW * NC) + pix * NC + ch] = sum / (cy * cx);
}

// ---------------- coloring: out = sqrt(s)*Yf*rF + mean_s ----------------
// grid(36,8,2), block(16,16): 32 ch x 64 n tile. B read channel-last, transposed via LDS.
__launch_bounds__(256)
__global__ void coloring_kernel(const float* __restrict__ Yf, const double* __restrict__ snorm,
                                const double* __restrict__ mean, const float* __restrict__ rF_cl,
                                float* __restrict__ out) {
  int b = blockIdx.z;
  const float* A = Yf + (2 + b) * MATSZ;
  const float* Bp = rF_cl + b * (HW * NC);
  const double* mn = mean + (2 + b) * NC;
  float cscale = (float)sqrt(snorm[2 + b]);
  int m0 = blockIdx.y * 32, n0 = blockIdx.x * 64;
  __shared__ float As[32][33];
  __shared__ float Bs[32][65];
  int tx = threadIdx.x, ty = threadIdx.y;
  int tid = ty * 16 + tx;
  float acc[2][4] = {};
  for (int k0 = 0; k0 < 256; k0 += 32) {
    __syncthreads();
    #pragma unroll
    for (int l = 0; l < 4; ++l) {
      int idx = tid + l * 256;
      int r = idx >> 5, cc = idx & 31;
      As[r][cc] = A[(m0 + r) * NC + k0 + cc];
    }
    #pragma unroll
    for (int l = 0; l < 8; ++l) {
      int idx = tid + l * 256;
      int kk = idx & 31, nn = idx >> 5;
      Bs[kk][nn] = Bp[(n0 + nn) * NC + k0 + kk];
    }
    __syncthreads();
    #pragma unroll
    for (int kk = 0; kk < 32; ++kk) {
      float a0 = As[ty][kk], a1 = As[ty + 16][kk];
      float b0 = Bs[kk][tx], b1 = Bs[kk][tx + 16], b2 = Bs[kk][tx + 32], b3 = Bs[kk][tx + 48];
      acc[0][0] += a0 * b0; acc[0][1] += a0 * b1; acc[0][2] += a0 * b2; acc[0][3] += a0 * b3;
      acc[1][0] += a1 * b0; acc[1][1] += a1 * b1; acc[1][2] += a1 * b2; acc[1][3] += a1 * b3;
    }
  }
  #pragma unroll
  for (int i = 0; i < 2; ++i) {
    int row = m0 + ty + 16 * i;
    float madd = (float)mn[row];
    #pragma unroll
    for (int j = 0; j < 4; ++j) {
      int n = n0 + tx + 16 * j;
      out[b * (NC * HW) + row * HW + n] = acc[i][j] * cscale + madd;
    }
  }
}

// ---------------- host ----------------
extern "C" void kernel_launch(void* const* d_in, const int* in_sizes, int n_in,
                              void* d_out, int out_size, void* d_ws, size_t ws_size,
                              hipStream_t stream) {
  const float* c = (const float*)d_in[0];
  const float* s = (const float*)d_in[1];
  float* out = (float*)d_out;

  char* ws = (char*)d_ws;
  size_t off = 0;
  auto alloc = [&](size_t bytes) {
    void* p = ws + off;
    off = (off + bytes + 255) & ~(size_t)255;
    return p;
  };
  double* mean   = (double*)alloc(4 * NC * sizeof(double));
  double* snorm  = (double*)alloc(4 * sizeof(double));
  float* cov     = (float*)alloc((size_t)4 * MATSZ * sizeof(float));
  float* Ya      = (float*)alloc((size_t)4 * MATSZ * sizeof(float));
  float* Yb      = (float*)alloc((size_t)4 * MATSZ * sizeof(float));
  float* Za      = (float*)alloc((size_t)4 * MATSZ * sizeof(float));
  float* Zb      = (float*)alloc((size_t)4 * MATSZ * sizeof(float));
  float* T       = (float*)alloc((size_t)4 * MATSZ * sizeof(float));
  float* padC_cf = (float*)alloc((size_t)2 * NC * NPIX * sizeof(float));
  float* padS_cf = (float*)alloc((size_t)2 * NC * NPIX * sizeof(float));
  float* padS_cl = (float*)alloc((size_t)2 * NPIX * NC * sizeof(float));
  float* rknorm  = (float*)alloc((size_t)2 * HW * sizeof(float));
  int*   ridx    = (int*)alloc((size_t)2 * HW * sizeof(int));
  float* rF_cl   = (float*)alloc((size_t)2 * HW * NC * sizeof(float));
  float* scores  = (float*)alloc((size_t)HW * HW * sizeof(float));  // one batch at a time

  mean_kernel<<<dim3(256, 4), 64, 0, stream>>>(c, s, mean);
  cov_kernel<<<dim3(16, 16, 4), dim3(16, 16), 0, stream>>>(c, s, mean, cov);
  trace_kernel<<<4, 256, 0, stream>>>(cov, snorm);
  ns_init<<<dim3(256, 4), 256, 0, stream>>>(cov, snorm, Ya, Za);

  float *Yc = Ya, *Zc = Za, *Yn = Yb, *Zn = Zb;
  for (int it = 0; it < NS_ITERS; ++it) {
    ns_gemm_T<<<dim3(8, 8, 4), dim3(16, 16), 0, stream>>>(Zc, Yc, T);
    ns_gemm_YZ<<<dim3(8, 8, 8), dim3(16, 16), 0, stream>>>(Yc, Zc, T, Yn, Zn);
    float* t1 = Yc; Yc = Yn; Yn = t1;
    float* t2 = Zc; Zc = Zn; Zn = t2;
  }

  hipMemsetAsync(padC_cf, 0, (size_t)2 * NC * NPIX * sizeof(float), stream);
  hipMemsetAsync(padS_cf, 0, (size_t)2 * NC * NPIX * sizeof(float), stream);
  hipMemsetAsync(padS_cl, 0, (size_t)2 * NPIX * NC * sizeof(float), stream);

  whiten_kernel<<<dim3(36, 8, 4), dim3(16, 16), 0, stream>>>(c, s, Zc, snorm, mean,
                                                             padC_cf, padS_cf, padS_cl);
  knorm_kernel<<<dim3(2304, 2), 256, 0, stream>>>(padS_cl, rknorm);

  for (int b = 0; b < 2; ++b) {
    score_gemm<<<dim3(36, 36), dim3(16, 16), 0, stream>>>(padC_cf, padS_cf, scores, b);
    argmax_kernel<<<dim3(2304), 256, 0, stream>>>(scores, rknorm, ridx, b);
  }

  reassemble_kernel<<<dim3(2304, 2), 256, 0, stream>>>(padS_cl, ridx, rF_cl);
  coloring_kernel<<<dim3(36, 8, 2), dim3(16, 16), 0, stream>>>(Yc, snorm, mean, rF_cl, out);
}

// Round 5
// 524.375 us; speedup vs baseline: 2.4580x; 2.4580x over previous
//
#include <hip/hip_runtime.h>
#include <math.h>

#define HW 2304       // 48*48
#define NC 256        // channels
#define NPIX 2500     // 50*50 padded grid (channel-last buffer)
#define NPIXP 2560    // padded row stride for channel-first buffers / Gram
#define MATSZ 65536   // 256*256
#define NS_ITERS 8

typedef unsigned long long u64;

// ---------------- reduction helper (block of 256) ----------------
__device__ __forceinline__ double blockReduceSum256(double v, double* sd) {
  int t = threadIdx.x;
  sd[t] = v; __syncthreads();
  for (int s = 128; s > 0; s >>= 1) {
    if (t < s) sd[t] += sd[t + s];
    __syncthreads();
  }
  return sd[0];
}

// ---------------- means (f64) ----------------
__global__ void mean_kernel(const float* __restrict__ c, const float* __restrict__ s,
                            double* __restrict__ mean) {
  int ch = blockIdx.x, m = blockIdx.y;
  const float* src = (m < 2 ? c + m * (NC * HW) : s + (m - 2) * (NC * HW)) + ch * HW;
  double acc = 0.0;
  for (int n = threadIdx.x; n < HW; n += 64) acc += (double)src[n];
  for (int o = 32; o > 0; o >>= 1) acc += __shfl_down(acc, o);
  if (threadIdx.x == 0) mean[m * NC + ch] = acc / (double)HW;
}

// ---------------- covariance (f32, vectorized, centered-in-LDS) ----------------
// grid(16,16,4), block(16,16): 16x16 cov tile, K-chunk 128
__launch_bounds__(256)
__global__ void cov_kernel(const float* __restrict__ c, const float* __restrict__ s,
                           const double* __restrict__ mean, float* __restrict__ cov) {
  int m = blockIdx.z;
  const float* src = (m < 2 ? c + m * (NC * HW) : s + (m - 2) * (NC * HW));
  const double* mn = mean + m * NC;
  int i0 = blockIdx.y * 16, j0 = blockIdx.x * 16;
  __shared__ float a[16][132], b[16][132];
  int tx = threadIdx.x, ty = threadIdx.y;
  int tid = ty * 16 + tx;
  // each thread stages 2 float4 per buffer per chunk; row fixed per l
  int f40 = tid, f41 = tid + 256;
  int r0 = f40 >> 5, c40 = (f40 & 31) << 2;
  int r1 = f41 >> 5, c41 = (f41 & 31) << 2;
  float ma0 = (float)mn[i0 + r0], ma1 = (float)mn[i0 + r1];
  float mb0 = (float)mn[j0 + r0], mb1 = (float)mn[j0 + r1];
  float acc = 0.0f;
  for (int n0 = 0; n0 < HW; n0 += 128) {
    __syncthreads();
    float4 va0 = *(const float4*)&src[(i0 + r0) * HW + n0 + c40];
    float4 va1 = *(const float4*)&src[(i0 + r1) * HW + n0 + c41];
    float4 vb0 = *(const float4*)&src[(j0 + r0) * HW + n0 + c40];
    float4 vb1 = *(const float4*)&src[(j0 + r1) * HW + n0 + c41];
    va0.x -= ma0; va0.y -= ma0; va0.z -= ma0; va0.w -= ma0;
    va1.x -= ma1; va1.y -= ma1; va1.z -= ma1; va1.w -= ma1;
    vb0.x -= mb0; vb0.y -= mb0; vb0.z -= mb0; vb0.w -= mb0;
    vb1.x -= mb1; vb1.y -= mb1; vb1.z -= mb1; vb1.w -= mb1;
    *(float4*)&a[r0][c40] = va0; *(float4*)&a[r1][c41] = va1;
    *(float4*)&b[r0][c40] = vb0; *(float4*)&b[r1][c41] = vb1;
    __syncthreads();
    #pragma unroll
    for (int n4 = 0; n4 < 128; n4 += 4) {
      float4 va = *(const float4*)&a[ty][n4];
      float4 vb = *(const float4*)&b[tx][n4];
      acc += va.x * vb.x + va.y * vb.y + va.z * vb.z + va.w * vb.w;
    }
  }
  cov[m * MATSZ + (i0 + ty) * NC + j0 + tx] = acc;
}

// ---------------- trace -> NS scale ----------------
__global__ void trace_kernel(const float* __restrict__ cov, double* __restrict__ snorm) {
  int m = blockIdx.x, t = threadIdx.x;
  __shared__ double sd[256];
  double v = (double)cov[m * MATSZ + t * 257];
  double tr = blockReduceSum256(v, sd);
  if (t == 0) snorm[m] = 1.25 * tr / 256.0;
}

__global__ void ns_init(const float* __restrict__ cov, const double* __restrict__ snorm,
                        float* __restrict__ Y, float* __restrict__ Z) {
  int m = blockIdx.y;
  int e = blockIdx.x * 256 + threadIdx.x;
  double inv = 1.0 / snorm[m];
  Y[m * MATSZ + e] = (float)((double)cov[m * MATSZ + e] * inv);
  Z[m * MATSZ + e] = ((e >> 8) == (e & 255)) ? 1.0f : 0.0f;
}

// ---------------- Newton-Schulz GEMMs (256x256x256, f32) ----------------
__launch_bounds__(256)
__global__ void ns_gemm_T(const float* __restrict__ Zc, const float* __restrict__ Yc,
                          float* __restrict__ T) {
  int m = blockIdx.z;
  const float* A = Zc + m * MATSZ;
  const float* B = Yc + m * MATSZ;
  int m0 = blockIdx.y * 32, n0 = blockIdx.x * 32;
  __shared__ float As[32][33], Bs[32][33];
  int tx = threadIdx.x, ty = threadIdx.y;
  int tid = ty * 16 + tx;
  float acc[2][2] = {};
  for (int k0 = 0; k0 < 256; k0 += 32) {
    __syncthreads();
    #pragma unroll
    for (int l = 0; l < 4; ++l) {
      int idx = tid + l * 256;
      int r = idx >> 5, cc = idx & 31;
      As[r][cc] = A[(m0 + r) * NC + k0 + cc];
      Bs[r][cc] = B[(k0 + r) * NC + n0 + cc];
    }
    __syncthreads();
    #pragma unroll
    for (int kk = 0; kk < 32; ++kk) {
      float a0 = As[ty][kk], a1 = As[ty + 16][kk];
      float b0 = Bs[kk][tx], b1 = Bs[kk][tx + 16];
      acc[0][0] += a0 * b0; acc[0][1] += a0 * b1;
      acc[1][0] += a1 * b0; acc[1][1] += a1 * b1;
    }
  }
  float* Cp = T + m * MATSZ;
  #pragma unroll
  for (int i = 0; i < 2; ++i)
    #pragma unroll
    for (int j = 0; j < 2; ++j) {
      int row = m0 + ty + 16 * i, col = n0 + tx + 16 * j;
      Cp[row * NC + col] = (row == col ? 1.5f : 0.0f) - 0.5f * acc[i][j];
    }
}

__launch_bounds__(256)
__global__ void ns_gemm_YZ(const float* __restrict__ Yc, const float* __restrict__ Zc,
                           const float* __restrict__ T,
                           float* __restrict__ Yn, float* __restrict__ Zn) {
  int z = blockIdx.z;
  int m = z & 3;
  bool isY = (z < 4);
  const float* A = isY ? (Yc + m * MATSZ) : (T + m * MATSZ);
  const float* B = isY ? (T + m * MATSZ) : (Zc + m * MATSZ);
  float* Cp = isY ? (Yn + m * MATSZ) : (Zn + m * MATSZ);
  int m0 = blockIdx.y * 32, n0 = blockIdx.x * 32;
  __shared__ float As[32][33], Bs[32][33];
  int tx = threadIdx.x, ty = threadIdx.y;
  int tid = ty * 16 + tx;
  float acc[2][2] = {};
  for (int k0 = 0; k0 < 256; k0 += 32) {
    __syncthreads();
    #pragma unroll
    for (int l = 0; l < 4; ++l) {
      int idx = tid + l * 256;
      int r = idx >> 5, cc = idx & 31;
      As[r][cc] = A[(m0 + r) * NC + k0 + cc];
      Bs[r][cc] = B[(k0 + r) * NC + n0 + cc];
    }
    __syncthreads();
    #pragma unroll
    for (int kk = 0; kk < 32; ++kk) {
      float a0 = As[ty][kk], a1 = As[ty + 16][kk];
      float b0 = Bs[kk][tx], b1 = Bs[kk][tx + 16];
      acc[0][0] += a0 * b0; acc[0][1] += a0 * b1;
      acc[1][0] += a1 * b0; acc[1][1] += a1 * b1;
    }
  }
  #pragma unroll
  for (int i = 0; i < 2; ++i)
    #pragma unroll
    for (int j = 0; j < 2; ++j)
      Cp[(m0 + ty + 16 * i) * NC + n0 + tx + 16 * j] = acc[i][j];
}

// ---------------- whitening apply -> padded norm buffers ----------------
__launch_bounds__(256)
__global__ void whiten_kernel(const float* __restrict__ c, const float* __restrict__ s,
                              const float* __restrict__ Zf,
                              const double* __restrict__ snorm, const double* __restrict__ mean,
                              float* __restrict__ padC_cf, float* __restrict__ padS_cf,
                              float* __restrict__ padS_cl) {
  int mat = blockIdx.z;
  const float* src = (mat < 2 ? c + mat * (NC * HW) : s + (mat - 2) * (NC * HW));
  const float* A = Zf + mat * MATSZ;
  const double* mn = mean + mat * NC;
  float wscale = (float)(1.0 / sqrt(snorm[mat]));
  int m0 = blockIdx.y * 32, n0 = blockIdx.x * 64;
  __shared__ float As[32][33];
  __shared__ float Bs[32][65];
  int tx = threadIdx.x, ty = threadIdx.y;
  int tid = ty * 16 + tx;
  float acc[2][4] = {};
  for (int k0 = 0; k0 < 256; k0 += 32) {
    __syncthreads();
    #pragma unroll
    for (int l = 0; l < 4; ++l) {
      int idx = tid + l * 256;
      int r = idx >> 5, cc = idx & 31;
      As[r][cc] = A[(m0 + r) * NC + k0 + cc];
    }
    #pragma unroll
    for (int l = 0; l < 8; ++l) {
      int idx = tid + l * 256;
      int kk = idx >> 6, nn = idx & 63;
      Bs[kk][nn] = src[(k0 + kk) * HW + n0 + nn] - (float)mn[k0 + kk];
    }
    __syncthreads();
    #pragma unroll
    for (int kk = 0; kk < 32; ++kk) {
      float a0 = As[ty][kk], a1 = As[ty + 16][kk];
      float b0 = Bs[kk][tx], b1 = Bs[kk][tx + 16], b2 = Bs[kk][tx + 32], b3 = Bs[kk][tx + 48];
      acc[0][0] += a0 * b0; acc[0][1] += a0 * b1; acc[0][2] += a0 * b2; acc[0][3] += a0 * b3;
      acc[1][0] += a1 * b0; acc[1][1] += a1 * b1; acc[1][2] += a1 * b2; acc[1][3] += a1 * b3;
    }
  }
  #pragma unroll
  for (int i = 0; i < 2; ++i) {
    int row = m0 + ty + 16 * i;
    #pragma unroll
    for (int j = 0; j < 4; ++j) {
      int n = n0 + tx + 16 * j;
      float v = acc[i][j] * wscale;
      int y = n / 48, x = n % 48;
      int ppos = (y + 1) * 50 + (x + 1);
      if (mat < 2) {
        padC_cf[(u64)mat * (NC * NPIXP) + row * NPIXP + ppos] = v;
      } else {
        padS_cf[(u64)(mat - 2) * (NC * NPIXP) + row * NPIXP + ppos] = v;
        padS_cl[(u64)(mat - 2) * (NPIX * NC) + ppos * NC + row] = v;
      }
    }
  }
}

// ---------------- patch norms: rknorm = 1/||ker(ps)|| ----------------
__global__ void knorm_kernel(const float* __restrict__ padS_cl, float* __restrict__ rknorm) {
  int ps = blockIdx.x, b = blockIdx.y;
  int ys = ps / 48, xs = ps % 48;
  const float* S = padS_cl + (u64)b * (NPIX * NC);
  int ch = threadIdx.x;
  double acc = 0.0;
  #pragma unroll
  for (int dy = 0; dy < 3; ++dy)
    #pragma unroll
    for (int dx = 0; dx < 3; ++dx) {
      float v = S[((ys + dy) * 50 + xs + dx) * NC + ch];
      acc += (double)v * (double)v;
    }
  __shared__ double sd[256];
  double tot = blockReduceSum256(acc, sd);
  if (ch == 0) rknorm[b * HW + ps] = (float)(1.0 / sqrt(tot));
}

// ---------------- pixel Gram: G[p][q] = sum_ch padC[ch][p]*padS[ch][q] ----------------
// 128x128 tile, 8x8 per thread, K=256 chunk 16. grid(20,20), block(16,16).
__launch_bounds__(256)
__global__ void gram_gemm(const float* __restrict__ padC_cf, const float* __restrict__ padS_cf,
                          float* __restrict__ G, int b) {
  const float* A = padC_cf + (u64)b * (NC * NPIXP);
  const float* B = padS_cf + (u64)b * (NC * NPIXP);
  int p0 = blockIdx.x * 128, q0 = blockIdx.y * 128;
  __shared__ float As[16][128], Bs[16][128];
  int tx = threadIdx.x, ty = threadIdx.y;
  int tid = ty * 16 + tx;
  int f40 = tid, f41 = tid + 256;
  int r0 = f40 >> 5, c40 = (f40 & 31) << 2;
  int r1 = f41 >> 5, c41 = (f41 & 31) << 2;
  float acc[8][8] = {};
  for (int k0 = 0; k0 < 256; k0 += 16) {
    __syncthreads();
    *(float4*)&As[r0][c40] = *(const float4*)&A[(u64)(k0 + r0) * NPIXP + p0 + c40];
    *(float4*)&As[r1][c41] = *(const float4*)&A[(u64)(k0 + r1) * NPIXP + p0 + c41];
    *(float4*)&Bs[r0][c40] = *(const float4*)&B[(u64)(k0 + r0) * NPIXP + q0 + c40];
    *(float4*)&Bs[r1][c41] = *(const float4*)&B[(u64)(k0 + r1) * NPIXP + q0 + c41];
    __syncthreads();
    #pragma unroll
    for (int k = 0; k < 16; ++k) {
      float4 a0 = *(const float4*)&As[k][ty * 8];
      float4 a1 = *(const float4*)&As[k][ty * 8 + 4];
      float4 b0 = *(const float4*)&Bs[k][tx * 8];
      float4 b1 = *(const float4*)&Bs[k][tx * 8 + 4];
      float av[8] = {a0.x, a0.y, a0.z, a0.w, a1.x, a1.y, a1.z, a1.w};
      float bv[8] = {b0.x, b0.y, b0.z, b0.w, b1.x, b1.y, b1.z, b1.w};
      #pragma unroll
      for (int i = 0; i < 8; ++i)
        #pragma unroll
        for (int j = 0; j < 8; ++j) acc[i][j] += av[i] * bv[j];
    }
  }
  #pragma unroll
  for (int i = 0; i < 8; ++i) {
    int row = p0 + ty * 8 + i;
    float4 v0 = make_float4(acc[i][0], acc[i][1], acc[i][2], acc[i][3]);
    float4 v1 = make_float4(acc[i][4], acc[i][5], acc[i][6], acc[i][7]);
    *(float4*)&G[(u64)row * NPIXP + q0 + tx * 8] = v0;
    *(float4*)&G[(u64)row * NPIXP + q0 + tx * 8 + 4] = v1;
  }
}

// ---------------- stencil sum: scores from Gram, 9-point diagonal gather ----------------
// grid(48 y, 48 ys), block 256. LDS stages 3 x 50x50 G blocks (same-dy bands).
__launch_bounds__(256)
__global__ void stencil_kernel(const float* __restrict__ G, float* __restrict__ scores) {
  int y = blockIdx.x, ys = blockIdx.y;
  __shared__ float Gt[3][50][50];
  int tid = threadIdx.x;
  for (int t = tid; t < 7500; t += 256) {
    int dy = t / 2500, rem = t % 2500;
    int u = rem / 50, v = rem - u * 50;
    Gt[dy][u][v] = G[(u64)((y + dy) * 50 + u) * NPIXP + (ys + dy) * 50 + v];
  }
  __syncthreads();
  #pragma unroll
  for (int k = 0; k < 9; ++k) {
    int idx = tid + k * 256;
    int x = idx / 48, xs = idx - x * 48;
    float sc = 0.0f;
    #pragma unroll
    for (int dy = 0; dy < 3; ++dy)
      #pragma unroll
      for (int dx = 0; dx < 3; ++dx)
        sc += Gt[dy][x + dx][xs + dx];
    scores[(u64)(y * 48 + x) * HW + ys * 48 + xs] = sc;
  }
}

// ---------------- argmax over ps (first-max tie-break) ----------------
__global__ void argmax_kernel(const float* __restrict__ scores, const float* __restrict__ rknorm,
                              int* __restrict__ ridx, int b) {
  int pc = blockIdx.x;
  const float* row = scores + (u64)pc * HW;
  const float* rk = rknorm + b * HW;
  int t = threadIdx.x;
  float best = -1e30f; int bi = 0;
  for (int ps = t; ps < HW; ps += 256) {
    float v = row[ps] * rk[ps];
    if (v > best) { best = v; bi = ps; }
  }
  __shared__ float sv[256]; __shared__ int si[256];
  sv[t] = best; si[t] = bi; __syncthreads();
  for (int s = 128; s > 0; s >>= 1) {
    if (t < s) {
      if (sv[t + s] > sv[t] || (sv[t + s] == sv[t] && si[t + s] < si[t])) {
        sv[t] = sv[t + s]; si[t] = si[t + s];
      }
    }
    __syncthreads();
  }
  if (t == 0) ridx[b * HW + pc] = si[0];
}

// ---------------- reassemble: paste chosen patches + overlap normalize ----------------
__global__ void reassemble_kernel(const float* __restrict__ padS_cl, const int* __restrict__ ridx,
                                  float* __restrict__ rF_cl) {
  int pix = blockIdx.x, b = blockIdx.y;
  int y = pix / 48, x = pix % 48;
  const int* idx = ridx + b * HW;
  const float* S = padS_cl + (u64)b * (NPIX * NC);
  int ch = threadIdx.x;
  float sum = 0.0f;
  #pragma unroll
  for (int i = 0; i < 3; ++i)
    #pragma unroll
    for (int j = 0; j < 3; ++j) {
      int yn = y + 1 - i, xn = x + 1 - j;
      if (yn >= 0 && yn < 48 && xn >= 0 && xn < 48) {
        int ps = idx[yn * 48 + xn];
        int ys = ps / 48, xs = ps % 48;
        sum += S[((ys + i) * 50 + xs + j) * NC + ch];
      }
    }
  float cy = (y == 0 || y == 47) ? 2.0f : 3.0f;
  float cx = (x == 0 || x == 47) ? 2.0f : 3.0f;
  rF_cl[(u64)b * (HW * NC) + pix * NC + ch] = sum / (cy * cx);
}

// ---------------- coloring: out = sqrt(s)*Yf*rF + mean_s ----------------
__launch_bounds__(256)
__global__ void coloring_kernel(const float* __restrict__ Yf, const double* __restrict__ snorm,
                                const double* __restrict__ mean, const float* __restrict__ rF_cl,
                                float* __restrict__ out) {
  int b = blockIdx.z;
  const float* A = Yf + (2 + b) * MATSZ;
  const float* Bp = rF_cl + (u64)b * (HW * NC);
  const double* mn = mean + (2 + b) * NC;
  float cscale = (float)sqrt(snorm[2 + b]);
  int m0 = blockIdx.y * 32, n0 = blockIdx.x * 64;
  __shared__ float As[32][33];
  __shared__ float Bs[32][65];
  int tx = threadIdx.x, ty = threadIdx.y;
  int tid = ty * 16 + tx;
  float acc[2][4] = {};
  for (int k0 = 0; k0 < 256; k0 += 32) {
    __syncthreads();
    #pragma unroll
    for (int l = 0; l < 4; ++l) {
      int idx = tid + l * 256;
      int r = idx >> 5, cc = idx & 31;
      As[r][cc] = A[(m0 + r) * NC + k0 + cc];
    }
    #pragma unroll
    for (int l = 0; l < 8; ++l) {
      int idx = tid + l * 256;
      int kk = idx & 31, nn = idx >> 5;
      Bs[kk][nn] = Bp[(u64)(n0 + nn) * NC + k0 + kk];
    }
    __syncthreads();
    #pragma unroll
    for (int kk = 0; kk < 32; ++kk) {
      float a0 = As[ty][kk], a1 = As[ty + 16][kk];
      float b0 = Bs[kk][tx], b1 = Bs[kk][tx + 16], b2 = Bs[kk][tx + 32], b3 = Bs[kk][tx + 48];
      acc[0][0] += a0 * b0; acc[0][1] += a0 * b1; acc[0][2] += a0 * b2; acc[0][3] += a0 * b3;
      acc[1][0] += a1 * b0; acc[1][1] += a1 * b1; acc[1][2] += a1 * b2; acc[1][3] += a1 * b3;
    }
  }
  #pragma unroll
  for (int i = 0; i < 2; ++i) {
    int row = m0 + ty + 16 * i;
    float madd = (float)mn[row];
    #pragma unroll
    for (int j = 0; j < 4; ++j) {
      int n = n0 + tx + 16 * j;
      out[(u64)b * (NC * HW) + row * HW + n] = acc[i][j] * cscale + madd;
    }
  }
}

// ---------------- host ----------------
extern "C" void kernel_launch(void* const* d_in, const int* in_sizes, int n_in,
                              void* d_out, int out_size, void* d_ws, size_t ws_size,
                              hipStream_t stream) {
  const float* c = (const float*)d_in[0];
  const float* s = (const float*)d_in[1];
  float* out = (float*)d_out;

  char* ws = (char*)d_ws;
  size_t off = 0;
  auto alloc = [&](size_t bytes) {
    void* p = ws + off;
    off = (off + bytes + 255) & ~(size_t)255;
    return p;
  };
  double* mean   = (double*)alloc(4 * NC * sizeof(double));
  double* snorm  = (double*)alloc(4 * sizeof(double));
  float* cov     = (float*)alloc((size_t)4 * MATSZ * sizeof(float));
  float* Ya      = (float*)alloc((size_t)4 * MATSZ * sizeof(float));
  float* Yb      = (float*)alloc((size_t)4 * MATSZ * sizeof(float));
  float* Za      = (float*)alloc((size_t)4 * MATSZ * sizeof(float));
  float* Zb      = (float*)alloc((size_t)4 * MATSZ * sizeof(float));
  float* T       = (float*)alloc((size_t)4 * MATSZ * sizeof(float));
  float* padC_cf = (float*)alloc((size_t)2 * NC * NPIXP * sizeof(float));
  float* padS_cf = (float*)alloc((size_t)2 * NC * NPIXP * sizeof(float));
  float* padS_cl = (float*)alloc((size_t)2 * NPIX * NC * sizeof(float));
  float* rknorm  = (float*)alloc((size_t)2 * HW * sizeof(float));
  int*   ridx    = (int*)alloc((size_t)2 * HW * sizeof(int));
  float* rF_cl   = (float*)alloc((size_t)2 * HW * NC * sizeof(float));
  float* scores  = (float*)alloc((size_t)HW * HW * sizeof(float));       // per-batch
  float* G       = (float*)alloc((size_t)NPIXP * NPIXP * sizeof(float)); // per-batch Gram

  mean_kernel<<<dim3(256, 4), 64, 0, stream>>>(c, s, mean);
  cov_kernel<<<dim3(16, 16, 4), dim3(16, 16), 0, stream>>>(c, s, mean, cov);
  trace_kernel<<<4, 256, 0, stream>>>(cov, snorm);
  ns_init<<<dim3(256, 4), 256, 0, stream>>>(cov, snorm, Ya, Za);

  float *Yc = Ya, *Zc = Za, *Yn = Yb, *Zn = Zb;
  for (int it = 0; it < NS_ITERS; ++it) {
    ns_gemm_T<<<dim3(8, 8, 4), dim3(16, 16), 0, stream>>>(Zc, Yc, T);
    ns_gemm_YZ<<<dim3(8, 8, 8), dim3(16, 16), 0, stream>>>(Yc, Zc, T, Yn, Zn);
    float* t1 = Yc; Yc = Yn; Yn = t1;
    float* t2 = Zc; Zc = Zn; Zn = t2;
  }

  hipMemsetAsync(padC_cf, 0, (size_t)2 * NC * NPIXP * sizeof(float), stream);
  hipMemsetAsync(padS_cf, 0, (size_t)2 * NC * NPIXP * sizeof(float), stream);
  hipMemsetAsync(padS_cl, 0, (size_t)2 * NPIX * NC * sizeof(float), stream);

  whiten_kernel<<<dim3(36, 8, 4), dim3(16, 16), 0, stream>>>(c, s, Zc, snorm, mean,
                                                             padC_cf, padS_cf, padS_cl);
  knorm_kernel<<<dim3(2304, 2), 256, 0, stream>>>(padS_cl, rknorm);

  for (int b = 0; b < 2; ++b) {
    gram_gemm<<<dim3(20, 20), dim3(16, 16), 0, stream>>>(padC_cf, padS_cf, G, b);
    stencil_kernel<<<dim3(48, 48), 256, 0, stream>>>(G, scores);
    argmax_kernel<<<dim3(2304), 256, 0, stream>>>(scores, rknorm, ridx, b);
  }

  reassemble_kernel<<<dim3(2304, 2), 256, 0, stream>>>(padS_cl, ridx, rF_cl);
  coloring_kernel<<<dim3(36, 8, 2), dim3(16, 16), 0, stream>>>(Yc, snorm, mean, rF_cl, out);
}

// Round 6
// 451.662 us; speedup vs baseline: 2.8537x; 1.1610x over previous
//
#include <hip/hip_runtime.h>
#include <math.h>

#define HW 2304       // 48*48
#define NC 256        // channels
#define NPIX 2500     // 50*50 padded grid (channel-last buffer)
#define NPIXP 2560    // padded row stride for channel-first buffers / Gram
#define MATSZ 65536   // 256*256
#define NS_ITERS 6    // |e5|~1e-12 from e0=0.64; f32-converged
#define NSLAB 6
#define KSLAB 384     // 2304/6

typedef unsigned long long u64;

// ---------------- reduction helper (block of 256) ----------------
__device__ __forceinline__ double blockReduceSum256(double v, double* sd) {
  int t = threadIdx.x;
  sd[t] = v; __syncthreads();
  for (int s = 128; s > 0; s >>= 1) {
    if (t < s) sd[t] += sd[t + s];
    __syncthreads();
  }
  return sd[0];
}

// ---------------- means (f64) ----------------
__global__ void mean_kernel(const float* __restrict__ c, const float* __restrict__ s,
                            double* __restrict__ mean) {
  int ch = blockIdx.x, m = blockIdx.y;
  const float* src = (m < 2 ? c + m * (NC * HW) : s + (m - 2) * (NC * HW)) + ch * HW;
  double acc = 0.0;
  for (int n = threadIdx.x; n < HW; n += 64) acc += (double)src[n];
  for (int o = 32; o > 0; o >>= 1) acc += __shfl_down(acc, o);
  if (threadIdx.x == 0) mean[m * NC + ch] = acc / (double)HW;
}

// ---------------- covariance partials: 64x64 tile, 4x4/thread, K-slab ----------------
// grid(4,4, 4*NSLAB), block(16,16). covp[z][256x256], z = m*NSLAB+slab.
__launch_bounds__(256)
__global__ void cov_part(const float* __restrict__ c, const float* __restrict__ s,
                         const double* __restrict__ mean, float* __restrict__ covp) {
  int z = blockIdx.z;
  int m = z / NSLAB, slab = z % NSLAB;
  const float* src = (m < 2 ? c + m * (NC * HW) : s + (m - 2) * (NC * HW));
  const double* mn = mean + m * NC;
  int i0 = blockIdx.y * 64, j0 = blockIdx.x * 64;
  int kb = slab * KSLAB;
  __shared__ float As[16][64], Bs[16][64];
  int tx = threadIdx.x, ty = threadIdx.y;
  int tid = ty * 16 + tx;
  int li = tid >> 2;        // row 0..63
  int lk4 = tid & 3;        // float4 group along k
  float mi = (float)mn[i0 + li];
  float mj = (float)mn[j0 + li];
  float acc[4][4] = {};
  for (int kc = 0; kc < KSLAB; kc += 16) {
    __syncthreads();
    float4 va = *(const float4*)&src[(u64)(i0 + li) * HW + kb + kc + lk4 * 4];
    float4 vb = *(const float4*)&src[(u64)(j0 + li) * HW + kb + kc + lk4 * 4];
    As[lk4 * 4 + 0][li] = va.x - mi; As[lk4 * 4 + 1][li] = va.y - mi;
    As[lk4 * 4 + 2][li] = va.z - mi; As[lk4 * 4 + 3][li] = va.w - mi;
    Bs[lk4 * 4 + 0][li] = vb.x - mj; Bs[lk4 * 4 + 1][li] = vb.y - mj;
    Bs[lk4 * 4 + 2][li] = vb.z - mj; Bs[lk4 * 4 + 3][li] = vb.w - mj;
    __syncthreads();
    #pragma unroll
    for (int kk = 0; kk < 16; ++kk) {
      float4 a = *(const float4*)&As[kk][ty * 4];
      float4 b = *(const float4*)&Bs[kk][tx * 4];
      float av[4] = {a.x, a.y, a.z, a.w};
      float bv[4] = {b.x, b.y, b.z, b.w};
      #pragma unroll
      for (int i = 0; i < 4; ++i)
        #pragma unroll
        for (int j = 0; j < 4; ++j) acc[i][j] += av[i] * bv[j];
    }
  }
  float* Cp = covp + (u64)z * MATSZ;
  #pragma unroll
  for (int i = 0; i < 4; ++i) {
    float4 v = make_float4(acc[i][0], acc[i][1], acc[i][2], acc[i][3]);
    *(float4*)&Cp[(i0 + ty * 4 + i) * NC + j0 + tx * 4] = v;
  }
}

// grid(256,4), block 256
__global__ void cov_reduce(const float* __restrict__ covp, float* __restrict__ cov) {
  int m = blockIdx.y;
  int e = blockIdx.x * 256 + threadIdx.x;
  float v = 0.0f;
  #pragma unroll
  for (int slab = 0; slab < NSLAB; ++slab)
    v += covp[(u64)(m * NSLAB + slab) * MATSZ + e];
  cov[m * MATSZ + e] = v;
}

// ---------------- trace -> NS scale ----------------
__global__ void trace_kernel(const float* __restrict__ cov, double* __restrict__ snorm) {
  int m = blockIdx.x, t = threadIdx.x;
  __shared__ double sd[256];
  double v = (double)cov[m * MATSZ + t * 257];
  double tr = blockReduceSum256(v, sd);
  if (t == 0) snorm[m] = 1.25 * tr / 256.0;
}

__global__ void ns_init(const float* __restrict__ cov, const double* __restrict__ snorm,
                        float* __restrict__ Y, float* __restrict__ Z) {
  int m = blockIdx.y;
  int e = blockIdx.x * 256 + threadIdx.x;
  double inv = 1.0 / snorm[m];
  Y[m * MATSZ + e] = (float)((double)cov[m * MATSZ + e] * inv);
  Z[m * MATSZ + e] = ((e >> 8) == (e & 255)) ? 1.0f : 0.0f;
}

// ---------------- Newton-Schulz GEMMs (256x256x256, f32) ----------------
__launch_bounds__(256)
__global__ void ns_gemm_T(const float* __restrict__ Zc, const float* __restrict__ Yc,
                          float* __restrict__ T) {
  int m = blockIdx.z;
  const float* A = Zc + m * MATSZ;
  const float* B = Yc + m * MATSZ;
  int m0 = blockIdx.y * 32, n0 = blockIdx.x * 32;
  __shared__ float As[32][33], Bs[32][33];
  int tx = threadIdx.x, ty = threadIdx.y;
  int tid = ty * 16 + tx;
  float acc[2][2] = {};
  for (int k0 = 0; k0 < 256; k0 += 32) {
    __syncthreads();
    #pragma unroll
    for (int l = 0; l < 4; ++l) {
      int idx = tid + l * 256;
      int r = idx >> 5, cc = idx & 31;
      As[r][cc] = A[(m0 + r) * NC + k0 + cc];
      Bs[r][cc] = B[(k0 + r) * NC + n0 + cc];
    }
    __syncthreads();
    #pragma unroll
    for (int kk = 0; kk < 32; ++kk) {
      float a0 = As[ty][kk], a1 = As[ty + 16][kk];
      float b0 = Bs[kk][tx], b1 = Bs[kk][tx + 16];
      acc[0][0] += a0 * b0; acc[0][1] += a0 * b1;
      acc[1][0] += a1 * b0; acc[1][1] += a1 * b1;
    }
  }
  float* Cp = T + m * MATSZ;
  #pragma unroll
  for (int i = 0; i < 2; ++i)
    #pragma unroll
    for (int j = 0; j < 2; ++j) {
      int row = m0 + ty + 16 * i, col = n0 + tx + 16 * j;
      Cp[row * NC + col] = (row == col ? 1.5f : 0.0f) - 0.5f * acc[i][j];
    }
}

__launch_bounds__(256)
__global__ void ns_gemm_YZ(const float* __restrict__ Yc, const float* __restrict__ Zc,
                           const float* __restrict__ T,
                           float* __restrict__ Yn, float* __restrict__ Zn) {
  int z = blockIdx.z;
  int m = z & 3;
  bool isY = (z < 4);
  const float* A = isY ? (Yc + m * MATSZ) : (T + m * MATSZ);
  const float* B = isY ? (T + m * MATSZ) : (Zc + m * MATSZ);
  float* Cp = isY ? (Yn + m * MATSZ) : (Zn + m * MATSZ);
  int m0 = blockIdx.y * 32, n0 = blockIdx.x * 32;
  __shared__ float As[32][33], Bs[32][33];
  int tx = threadIdx.x, ty = threadIdx.y;
  int tid = ty * 16 + tx;
  float acc[2][2] = {};
  for (int k0 = 0; k0 < 256; k0 += 32) {
    __syncthreads();
    #pragma unroll
    for (int l = 0; l < 4; ++l) {
      int idx = tid + l * 256;
      int r = idx >> 5, cc = idx & 31;
      As[r][cc] = A[(m0 + r) * NC + k0 + cc];
      Bs[r][cc] = B[(k0 + r) * NC + n0 + cc];
    }
    __syncthreads();
    #pragma unroll
    for (int kk = 0; kk < 32; ++kk) {
      float a0 = As[ty][kk], a1 = As[ty + 16][kk];
      float b0 = Bs[kk][tx], b1 = Bs[kk][tx + 16];
      acc[0][0] += a0 * b0; acc[0][1] += a0 * b1;
      acc[1][0] += a1 * b0; acc[1][1] += a1 * b1;
    }
  }
  #pragma unroll
  for (int i = 0; i < 2; ++i)
    #pragma unroll
    for (int j = 0; j < 2; ++j)
      Cp[(m0 + ty + 16 * i) * NC + n0 + tx + 16 * j] = acc[i][j];
}

// ---------------- whitening apply -> padded norm buffers ----------------
__launch_bounds__(256)
__global__ void whiten_kernel(const float* __restrict__ c, const float* __restrict__ s,
                              const float* __restrict__ Zf,
                              const double* __restrict__ snorm, const double* __restrict__ mean,
                              float* __restrict__ padC_cf, float* __restrict__ padS_cf,
                              float* __restrict__ padS_cl) {
  int mat = blockIdx.z;
  const float* src = (mat < 2 ? c + mat * (NC * HW) : s + (mat - 2) * (NC * HW));
  const float* A = Zf + mat * MATSZ;
  const double* mn = mean + mat * NC;
  float wscale = (float)(1.0 / sqrt(snorm[mat]));
  int m0 = blockIdx.y * 32, n0 = blockIdx.x * 64;
  __shared__ float As[32][33];
  __shared__ float Bs[32][65];
  int tx = threadIdx.x, ty = threadIdx.y;
  int tid = ty * 16 + tx;
  float acc[2][4] = {};
  for (int k0 = 0; k0 < 256; k0 += 32) {
    __syncthreads();
    #pragma unroll
    for (int l = 0; l < 4; ++l) {
      int idx = tid + l * 256;
      int r = idx >> 5, cc = idx & 31;
      As[r][cc] = A[(m0 + r) * NC + k0 + cc];
    }
    #pragma unroll
    for (int l = 0; l < 8; ++l) {
      int idx = tid + l * 256;
      int kk = idx >> 6, nn = idx & 63;
      Bs[kk][nn] = src[(k0 + kk) * HW + n0 + nn] - (float)mn[k0 + kk];
    }
    __syncthreads();
    #pragma unroll
    for (int kk = 0; kk < 32; ++kk) {
      float a0 = As[ty][kk], a1 = As[ty + 16][kk];
      float b0 = Bs[kk][tx], b1 = Bs[kk][tx + 16], b2 = Bs[kk][tx + 32], b3 = Bs[kk][tx + 48];
      acc[0][0] += a0 * b0; acc[0][1] += a0 * b1; acc[0][2] += a0 * b2; acc[0][3] += a0 * b3;
      acc[1][0] += a1 * b0; acc[1][1] += a1 * b1; acc[1][2] += a1 * b2; acc[1][3] += a1 * b3;
    }
  }
  #pragma unroll
  for (int i = 0; i < 2; ++i) {
    int row = m0 + ty + 16 * i;
    #pragma unroll
    for (int j = 0; j < 4; ++j) {
      int n = n0 + tx + 16 * j;
      float v = acc[i][j] * wscale;
      int y = n / 48, x = n % 48;
      int ppos = (y + 1) * 50 + (x + 1);
      if (mat < 2) {
        padC_cf[(u64)mat * (NC * NPIXP) + row * NPIXP + ppos] = v;
      } else {
        padS_cf[(u64)(mat - 2) * (NC * NPIXP) + row * NPIXP + ppos] = v;
        padS_cl[(u64)(mat - 2) * (NPIX * NC) + ppos * NC + row] = v;
      }
    }
  }
}

// ---------------- patch norms: rknorm = 1/||ker(ps)|| ----------------
__global__ void knorm_kernel(const float* __restrict__ padS_cl, float* __restrict__ rknorm) {
  int ps = blockIdx.x, b = blockIdx.y;
  int ys = ps / 48, xs = ps % 48;
  const float* S = padS_cl + (u64)b * (NPIX * NC);
  int ch = threadIdx.x;
  double acc = 0.0;
  #pragma unroll
  for (int dy = 0; dy < 3; ++dy)
    #pragma unroll
    for (int dx = 0; dx < 3; ++dx) {
      float v = S[((ys + dy) * 50 + xs + dx) * NC + ch];
      acc += (double)v * (double)v;
    }
  __shared__ double sd[256];
  double tot = blockReduceSum256(acc, sd);
  if (ch == 0) rknorm[b * HW + ps] = (float)(1.0 / sqrt(tot));
}

// ---------------- pixel Gram: G[p][q] = sum_ch padC[ch][p]*padS[ch][q] ----------------
__launch_bounds__(256)
__global__ void gram_gemm(const float* __restrict__ padC_cf, const float* __restrict__ padS_cf,
                          float* __restrict__ G, int b) {
  const float* A = padC_cf + (u64)b * (NC * NPIXP);
  const float* B = padS_cf + (u64)b * (NC * NPIXP);
  int p0 = blockIdx.x * 128, q0 = blockIdx.y * 128;
  __shared__ float As[16][128], Bs[16][128];
  int tx = threadIdx.x, ty = threadIdx.y;
  int tid = ty * 16 + tx;
  int f40 = tid, f41 = tid + 256;
  int r0 = f40 >> 5, c40 = (f40 & 31) << 2;
  int r1 = f41 >> 5, c41 = (f41 & 31) << 2;
  float acc[8][8] = {};
  for (int k0 = 0; k0 < 256; k0 += 16) {
    __syncthreads();
    *(float4*)&As[r0][c40] = *(const float4*)&A[(u64)(k0 + r0) * NPIXP + p0 + c40];
    *(float4*)&As[r1][c41] = *(const float4*)&A[(u64)(k0 + r1) * NPIXP + p0 + c41];
    *(float4*)&Bs[r0][c40] = *(const float4*)&B[(u64)(k0 + r0) * NPIXP + q0 + c40];
    *(float4*)&Bs[r1][c41] = *(const float4*)&B[(u64)(k0 + r1) * NPIXP + q0 + c41];
    __syncthreads();
    #pragma unroll
    for (int k = 0; k < 16; ++k) {
      float4 a0 = *(const float4*)&As[k][ty * 8];
      float4 a1 = *(const float4*)&As[k][ty * 8 + 4];
      float4 b0 = *(const float4*)&Bs[k][tx * 8];
      float4 b1 = *(const float4*)&Bs[k][tx * 8 + 4];
      float av[8] = {a0.x, a0.y, a0.z, a0.w, a1.x, a1.y, a1.z, a1.w};
      float bv[8] = {b0.x, b0.y, b0.z, b0.w, b1.x, b1.y, b1.z, b1.w};
      #pragma unroll
      for (int i = 0; i < 8; ++i)
        #pragma unroll
        for (int j = 0; j < 8; ++j) acc[i][j] += av[i] * bv[j];
    }
  }
  #pragma unroll
  for (int i = 0; i < 8; ++i) {
    int row = p0 + ty * 8 + i;
    float4 v0 = make_float4(acc[i][0], acc[i][1], acc[i][2], acc[i][3]);
    float4 v1 = make_float4(acc[i][4], acc[i][5], acc[i][6], acc[i][7]);
    *(float4*)&G[(u64)row * NPIXP + q0 + tx * 8] = v0;
    *(float4*)&G[(u64)row * NPIXP + q0 + tx * 8 + 4] = v1;
  }
}

// ---------------- fused stencil + argmax ----------------
// grid(48 y, 48 ys), block 256. Per-block best per pc row, packed u64 atomicMax.
// key = enc(score)<<32 | (2303-ps): deterministic first-max tie-break.
__launch_bounds__(256)
__global__ void scoremax_kernel(const float* __restrict__ G, const float* __restrict__ rknorm,
                                u64* __restrict__ rmax, int b) {
  int y = blockIdx.x, ys = blockIdx.y;
  __shared__ float Gt[3][50][50];
  __shared__ float sc[48][48];
  __shared__ float rkl[48];
  int tid = threadIdx.x;
  for (int t = tid; t < 7500; t += 256) {
    int dy = t / 2500, rem = t % 2500;
    int u = rem / 50, v = rem - u * 50;
    Gt[dy][u][v] = G[(u64)((y + dy) * 50 + u) * NPIXP + (ys + dy) * 50 + v];
  }
  if (tid < 48) rkl[tid] = rknorm[b * HW + ys * 48 + tid];
  __syncthreads();
  #pragma unroll
  for (int k = 0; k < 9; ++k) {
    int idx = tid + k * 256;
    int x = idx / 48, xs = idx - x * 48;
    float v = 0.0f;
    #pragma unroll
    for (int dy = 0; dy < 3; ++dy)
      #pragma unroll
      for (int dx = 0; dx < 3; ++dx)
        v += Gt[dy][x + dx][xs + dx];
    sc[x][xs] = v * rkl[xs];
  }
  __syncthreads();
  if (tid < 48) {
    float best = -1e30f; int bxs = 0;
    for (int xs = 0; xs < 48; ++xs) {
      float v = sc[tid][xs];
      if (v > best) { best = v; bxs = xs; }   // strict >: smallest xs on ties
    }
    int ps = ys * 48 + bxs;
    unsigned ub = __float_as_uint(best);
    unsigned enc = (ub & 0x80000000u) ? ~ub : (ub | 0x80000000u);
    u64 key = ((u64)enc << 32) | (u64)(2303 - ps);
    atomicMax(&rmax[(u64)b * HW + y * 48 + tid], key);
  }
}

// ---------------- reassemble: paste chosen patches + overlap normalize ----------------
__global__ void reassemble_kernel(const float* __restrict__ padS_cl, const u64* __restrict__ rmax,
                                  float* __restrict__ rF_cl) {
  int pix = blockIdx.x, b = blockIdx.y;
  int y = pix / 48, x = pix % 48;
  const u64* rm = rmax + (u64)b * HW;
  const float* S = padS_cl + (u64)b * (NPIX * NC);
  int ch = threadIdx.x;
  float sum = 0.0f;
  #pragma unroll
  for (int i = 0; i < 3; ++i)
    #pragma unroll
    for (int j = 0; j < 3; ++j) {
      int yn = y + 1 - i, xn = x + 1 - j;
      if (yn >= 0 && yn < 48 && xn >= 0 && xn < 48) {
        int ps = 2303 - (int)(unsigned)(rm[yn * 48 + xn] & 0xFFFFFFFFu);
        int ys = ps / 48, xs = ps % 48;
        sum += S[((ys + i) * 50 + xs + j) * NC + ch];
      }
    }
  float cy = (y == 0 || y == 47) ? 2.0f : 3.0f;
  float cx = (x == 0 || x == 47) ? 2.0f : 3.0f;
  rF_cl[(u64)b * (HW * NC) + pix * NC + ch] = sum / (cy * cx);
}

// ---------------- coloring: out = sqrt(s)*Yf*rF + mean_s ----------------
__launch_bounds__(256)
__global__ void coloring_kernel(const float* __restrict__ Yf, const double* __restrict__ snorm,
                                const double* __restrict__ mean, const float* __restrict__ rF_cl,
                                float* __restrict__ out) {
  int b = blockIdx.z;
  const float* A = Yf + (2 + b) * MATSZ;
  const float* Bp = rF_cl + (u64)b * (HW * NC);
  const double* mn = mean + (2 + b) * NC;
  float cscale = (float)sqrt(snorm[2 + b]);
  int m0 = blockIdx.y * 32, n0 = blockIdx.x * 64;
  __shared__ float As[32][33];
  __shared__ float Bs[32][65];
  int tx = threadIdx.x, ty = threadIdx.y;
  int tid = ty * 16 + tx;
  float acc[2][4] = {};
  for (int k0 = 0; k0 < 256; k0 += 32) {
    __syncthreads();
    #pragma unroll
    for (int l = 0; l < 4; ++l) {
      int idx = tid + l * 256;
      int r = idx >> 5, cc = idx & 31;
      As[r][cc] = A[(m0 + r) * NC + k0 + cc];
    }
    #pragma unroll
    for (int l = 0; l < 8; ++l) {
      int idx = tid + l * 256;
      int kk = idx & 31, nn = idx >> 5;
      Bs[kk][nn] = Bp[(u64)(n0 + nn) * NC + k0 + kk];
    }
    __syncthreads();
    #pragma unroll
    for (int kk = 0; kk < 32; ++kk) {
      float a0 = As[ty][kk], a1 = As[ty + 16][kk];
      float b0 = Bs[kk][tx], b1 = Bs[kk][tx + 16], b2 = Bs[kk][tx + 32], b3 = Bs[kk][tx + 48];
      acc[0][0] += a0 * b0; acc[0][1] += a0 * b1; acc[0][2] += a0 * b2; acc[0][3] += a0 * b3;
      acc[1][0] += a1 * b0; acc[1][1] += a1 * b1; acc[1][2] += a1 * b2; acc[1][3] += a1 * b3;
    }
  }
  #pragma unroll
  for (int i = 0; i < 2; ++i) {
    int row = m0 + ty + 16 * i;
    float madd = (float)mn[row];
    #pragma unroll
    for (int j = 0; j < 4; ++j) {
      int n = n0 + tx + 16 * j;
      out[(u64)b * (NC * HW) + row * HW + n] = acc[i][j] * cscale + madd;
    }
  }
}

// ---------------- host ----------------
extern "C" void kernel_launch(void* const* d_in, const int* in_sizes, int n_in,
                              void* d_out, int out_size, void* d_ws, size_t ws_size,
                              hipStream_t stream) {
  const float* c = (const float*)d_in[0];
  const float* s = (const float*)d_in[1];
  float* out = (float*)d_out;

  char* ws = (char*)d_ws;
  size_t off = 0;
  auto alloc = [&](size_t bytes) {
    void* p = ws + off;
    off = (off + bytes + 255) & ~(size_t)255;
    return p;
  };
  double* mean   = (double*)alloc(4 * NC * sizeof(double));
  double* snorm  = (double*)alloc(4 * sizeof(double));
  float* cov     = (float*)alloc((size_t)4 * MATSZ * sizeof(float));
  float* covp    = (float*)alloc((size_t)4 * NSLAB * MATSZ * sizeof(float));
  float* Ya      = (float*)alloc((size_t)4 * MATSZ * sizeof(float));
  float* Yb      = (float*)alloc((size_t)4 * MATSZ * sizeof(float));
  float* Za      = (float*)alloc((size_t)4 * MATSZ * sizeof(float));
  float* Zb      = (float*)alloc((size_t)4 * MATSZ * sizeof(float));
  float* T       = (float*)alloc((size_t)4 * MATSZ * sizeof(float));
  float* padC_cf = (float*)alloc((size_t)2 * NC * NPIXP * sizeof(float));
  float* padS_cf = (float*)alloc((size_t)2 * NC * NPIXP * sizeof(float));
  float* padS_cl = (float*)alloc((size_t)2 * NPIX * NC * sizeof(float));
  float* rknorm  = (float*)alloc((size_t)2 * HW * sizeof(float));
  u64*   rmax    = (u64*)alloc((size_t)2 * HW * sizeof(u64));
  float* rF_cl   = (float*)alloc((size_t)2 * HW * NC * sizeof(float));
  float* G       = (float*)alloc((size_t)NPIXP * NPIXP * sizeof(float)); // per-batch Gram

  mean_kernel<<<dim3(256, 4), 64, 0, stream>>>(c, s, mean);
  cov_part<<<dim3(4, 4, 4 * NSLAB), dim3(16, 16), 0, stream>>>(c, s, mean, covp);
  cov_reduce<<<dim3(256, 4), 256, 0, stream>>>(covp, cov);
  trace_kernel<<<4, 256, 0, stream>>>(cov, snorm);
  ns_init<<<dim3(256, 4), 256, 0, stream>>>(cov, snorm, Ya, Za);

  float *Yc = Ya, *Zc = Za, *Yn = Yb, *Zn = Zb;
  for (int it = 0; it < NS_ITERS; ++it) {
    ns_gemm_T<<<dim3(8, 8, 4), dim3(16, 16), 0, stream>>>(Zc, Yc, T);
    ns_gemm_YZ<<<dim3(8, 8, 8), dim3(16, 16), 0, stream>>>(Yc, Zc, T, Yn, Zn);
    float* t1 = Yc; Yc = Yn; Yn = t1;
    float* t2 = Zc; Zc = Zn; Zn = t2;
  }

  hipMemsetAsync(padC_cf, 0, (size_t)2 * NC * NPIXP * sizeof(float), stream);
  hipMemsetAsync(padS_cf, 0, (size_t)2 * NC * NPIXP * sizeof(float), stream);
  hipMemsetAsync(padS_cl, 0, (size_t)2 * NPIX * NC * sizeof(float), stream);
  hipMemsetAsync(rmax, 0, (size_t)2 * HW * sizeof(u64), stream);

  whiten_kernel<<<dim3(36, 8, 4), dim3(16, 16), 0, stream>>>(c, s, Zc, snorm, mean,
                                                             padC_cf, padS_cf, padS_cl);
  knorm_kernel<<<dim3(2304, 2), 256, 0, stream>>>(padS_cl, rknorm);

  for (int b = 0; b < 2; ++b) {
    gram_gemm<<<dim3(20, 20), dim3(16, 16), 0, stream>>>(padC_cf, padS_cf, G, b);
    scoremax_kernel<<<dim3(48, 48), 256, 0, stream>>>(G, rknorm, rmax, b);
  }

  reassemble_kernel<<<dim3(2304, 2), 256, 0, stream>>>(padS_cl, rmax, rF_cl);
  coloring_kernel<<<dim3(36, 8, 2), dim3(16, 16), 0, stream>>>(Yc, snorm, mean, rF_cl, out);
}

// Round 7
// 436.969 us; speedup vs baseline: 2.9496x; 1.0336x over previous
//
#include <hip/hip_runtime.h>
#include <math.h>

#define HW 2304       // 48*48
#define NC 256        // channels
#define NPIX 2500     // 50*50 padded grid (channel-last buffer)
#define NPIXP 2560    // padded row stride for channel-first buffers / Gram
#define MATSZ 65536   // 256*256
#define NS_ITERS 5    // e5 ~ 7e-9 from e0=0.644; f32-converged
#define NSLAB 6
#define KSLAB 384     // 2304/6

typedef unsigned long long u64;

// ---------------- means (f64) ----------------
__global__ void mean_kernel(const float* __restrict__ c, const float* __restrict__ s,
                            double* __restrict__ mean) {
  int ch = blockIdx.x, m = blockIdx.y;
  const float* src = (m < 2 ? c + m * (NC * HW) : s + (m - 2) * (NC * HW)) + ch * HW;
  double acc = 0.0;
  for (int n = threadIdx.x; n < HW; n += 64) acc += (double)src[n];
  for (int o = 32; o > 0; o >>= 1) acc += __shfl_down(acc, o);
  if (threadIdx.x == 0) mean[m * NC + ch] = acc / (double)HW;
}

// ---------------- covariance partials: raw sum(x*y), 64x64 tile, 4x4/thread ----------------
// grid(4,4, 4*NSLAB), block(16,16). covp[z][256x256], z = m*NSLAB+slab. No mean needed.
__launch_bounds__(256)
__global__ void cov_part(const float* __restrict__ c, const float* __restrict__ s,
                         float* __restrict__ covp) {
  int z = blockIdx.z;
  int m = z / NSLAB, slab = z % NSLAB;
  const float* src = (m < 2 ? c + m * (NC * HW) : s + (m - 2) * (NC * HW));
  int i0 = blockIdx.y * 64, j0 = blockIdx.x * 64;
  int kb = slab * KSLAB;
  __shared__ float As[16][64], Bs[16][64];
  int tx = threadIdx.x, ty = threadIdx.y;
  int tid = ty * 16 + tx;
  int li = tid >> 2;        // row 0..63
  int lk4 = tid & 3;        // float4 group along k
  float acc[4][4] = {};
  for (int kc = 0; kc < KSLAB; kc += 16) {
    __syncthreads();
    float4 va = *(const float4*)&src[(u64)(i0 + li) * HW + kb + kc + lk4 * 4];
    float4 vb = *(const float4*)&src[(u64)(j0 + li) * HW + kb + kc + lk4 * 4];
    As[lk4 * 4 + 0][li] = va.x; As[lk4 * 4 + 1][li] = va.y;
    As[lk4 * 4 + 2][li] = va.z; As[lk4 * 4 + 3][li] = va.w;
    Bs[lk4 * 4 + 0][li] = vb.x; Bs[lk4 * 4 + 1][li] = vb.y;
    Bs[lk4 * 4 + 2][li] = vb.z; Bs[lk4 * 4 + 3][li] = vb.w;
    __syncthreads();
    #pragma unroll
    for (int kk = 0; kk < 16; ++kk) {
      float4 a = *(const float4*)&As[kk][ty * 4];
      float4 b = *(const float4*)&Bs[kk][tx * 4];
      float av[4] = {a.x, a.y, a.z, a.w};
      float bv[4] = {b.x, b.y, b.z, b.w};
      #pragma unroll
      for (int i = 0; i < 4; ++i)
        #pragma unroll
        for (int j = 0; j < 4; ++j) acc[i][j] += av[i] * bv[j];
    }
  }
  float* Cp = covp + (u64)z * MATSZ;
  #pragma unroll
  for (int i = 0; i < 4; ++i) {
    float4 v = make_float4(acc[i][0], acc[i][1], acc[i][2], acc[i][3]);
    *(float4*)&Cp[(i0 + ty * 4 + i) * NC + j0 + tx * 4] = v;
  }
}

// grid(256,4), block 256: cov = sum(slabs) - HW*mu_i*mu_j; diag -> snorm (trace fused)
__global__ void cov_reduce(const float* __restrict__ covp, const double* __restrict__ mean,
                           float* __restrict__ cov, double* __restrict__ snorm) {
  int m = blockIdx.y;
  int row = blockIdx.x, col = threadIdx.x;
  int e = row * 256 + col;
  float v = 0.0f;
  #pragma unroll
  for (int slab = 0; slab < NSLAB; ++slab)
    v += covp[(u64)(m * NSLAB + slab) * MATSZ + e];
  double mi = mean[m * NC + row], mj = mean[m * NC + col];
  float res = (float)((double)v - (double)HW * mi * mj);
  cov[m * MATSZ + e] = res;
  if (col == row) atomicAdd(&snorm[m], 1.25 * (double)res / 256.0);
}

__global__ void ns_init(const float* __restrict__ cov, const double* __restrict__ snorm,
                        float* __restrict__ Y, float* __restrict__ Z) {
  int m = blockIdx.y;
  int e = blockIdx.x * 256 + threadIdx.x;
  double inv = 1.0 / snorm[m];
  Y[m * MATSZ + e] = (float)((double)cov[m * MATSZ + e] * inv);
  Z[m * MATSZ + e] = ((e >> 8) == (e & 255)) ? 1.0f : 0.0f;
}

// ---------------- Newton-Schulz GEMMs (256x256x256, f32) ----------------
__launch_bounds__(256)
__global__ void ns_gemm_T(const float* __restrict__ Zc, const float* __restrict__ Yc,
                          float* __restrict__ T) {
  int m = blockIdx.z;
  const float* A = Zc + m * MATSZ;
  const float* B = Yc + m * MATSZ;
  int m0 = blockIdx.y * 32, n0 = blockIdx.x * 32;
  __shared__ float As[32][33], Bs[32][33];
  int tx = threadIdx.x, ty = threadIdx.y;
  int tid = ty * 16 + tx;
  float acc[2][2] = {};
  for (int k0 = 0; k0 < 256; k0 += 32) {
    __syncthreads();
    #pragma unroll
    for (int l = 0; l < 4; ++l) {
      int idx = tid + l * 256;
      int r = idx >> 5, cc = idx & 31;
      As[r][cc] = A[(m0 + r) * NC + k0 + cc];
      Bs[r][cc] = B[(k0 + r) * NC + n0 + cc];
    }
    __syncthreads();
    #pragma unroll
    for (int kk = 0; kk < 32; ++kk) {
      float a0 = As[ty][kk], a1 = As[ty + 16][kk];
      float b0 = Bs[kk][tx], b1 = Bs[kk][tx + 16];
      acc[0][0] += a0 * b0; acc[0][1] += a0 * b1;
      acc[1][0] += a1 * b0; acc[1][1] += a1 * b1;
    }
  }
  float* Cp = T + m * MATSZ;
  #pragma unroll
  for (int i = 0; i < 2; ++i)
    #pragma unroll
    for (int j = 0; j < 2; ++j) {
      int row = m0 + ty + 16 * i, col = n0 + tx + 16 * j;
      Cp[row * NC + col] = (row == col ? 1.5f : 0.0f) - 0.5f * acc[i][j];
    }
}

__launch_bounds__(256)
__global__ void ns_gemm_YZ(const float* __restrict__ Yc, const float* __restrict__ Zc,
                           const float* __restrict__ T,
                           float* __restrict__ Yn, float* __restrict__ Zn) {
  int z = blockIdx.z;
  int m = z & 3;
  bool isY = (z < 4);
  const float* A = isY ? (Yc + m * MATSZ) : (T + m * MATSZ);
  const float* B = isY ? (T + m * MATSZ) : (Zc + m * MATSZ);
  float* Cp = isY ? (Yn + m * MATSZ) : (Zn + m * MATSZ);
  int m0 = blockIdx.y * 32, n0 = blockIdx.x * 32;
  __shared__ float As[32][33], Bs[32][33];
  int tx = threadIdx.x, ty = threadIdx.y;
  int tid = ty * 16 + tx;
  float acc[2][2] = {};
  for (int k0 = 0; k0 < 256; k0 += 32) {
    __syncthreads();
    #pragma unroll
    for (int l = 0; l < 4; ++l) {
      int idx = tid + l * 256;
      int r = idx >> 5, cc = idx & 31;
      As[r][cc] = A[(m0 + r) * NC + k0 + cc];
      Bs[r][cc] = B[(k0 + r) * NC + n0 + cc];
    }
    __syncthreads();
    #pragma unroll
    for (int kk = 0; kk < 32; ++kk) {
      float a0 = As[ty][kk], a1 = As[ty + 16][kk];
      float b0 = Bs[kk][tx], b1 = Bs[kk][tx + 16];
      acc[0][0] += a0 * b0; acc[0][1] += a0 * b1;
      acc[1][0] += a1 * b0; acc[1][1] += a1 * b1;
    }
  }
  #pragma unroll
  for (int i = 0; i < 2; ++i)
    #pragma unroll
    for (int j = 0; j < 2; ++j)
      Cp[(m0 + ty + 16 * i) * NC + n0 + tx + 16 * j] = acc[i][j];
}

// ---------------- whitening apply -> padded norm buffers ----------------
__launch_bounds__(256)
__global__ void whiten_kernel(const float* __restrict__ c, const float* __restrict__ s,
                              const float* __restrict__ Zf,
                              const double* __restrict__ snorm, const double* __restrict__ mean,
                              float* __restrict__ padC_cf, float* __restrict__ padS_cf,
                              float* __restrict__ padS_cl) {
  int mat = blockIdx.z;
  const float* src = (mat < 2 ? c + mat * (NC * HW) : s + (mat - 2) * (NC * HW));
  const float* A = Zf + mat * MATSZ;
  const double* mn = mean + mat * NC;
  float wscale = (float)(1.0 / sqrt(snorm[mat]));
  int m0 = blockIdx.y * 32, n0 = blockIdx.x * 64;
  __shared__ float As[32][33];
  __shared__ float Bs[32][65];
  int tx = threadIdx.x, ty = threadIdx.y;
  int tid = ty * 16 + tx;
  float acc[2][4] = {};
  for (int k0 = 0; k0 < 256; k0 += 32) {
    __syncthreads();
    #pragma unroll
    for (int l = 0; l < 4; ++l) {
      int idx = tid + l * 256;
      int r = idx >> 5, cc = idx & 31;
      As[r][cc] = A[(m0 + r) * NC + k0 + cc];
    }
    #pragma unroll
    for (int l = 0; l < 8; ++l) {
      int idx = tid + l * 256;
      int kk = idx >> 6, nn = idx & 63;
      Bs[kk][nn] = src[(k0 + kk) * HW + n0 + nn] - (float)mn[k0 + kk];
    }
    __syncthreads();
    #pragma unroll
    for (int kk = 0; kk < 32; ++kk) {
      float a0 = As[ty][kk], a1 = As[ty + 16][kk];
      float b0 = Bs[kk][tx], b1 = Bs[kk][tx + 16], b2 = Bs[kk][tx + 32], b3 = Bs[kk][tx + 48];
      acc[0][0] += a0 * b0; acc[0][1] += a0 * b1; acc[0][2] += a0 * b2; acc[0][3] += a0 * b3;
      acc[1][0] += a1 * b0; acc[1][1] += a1 * b1; acc[1][2] += a1 * b2; acc[1][3] += a1 * b3;
    }
  }
  #pragma unroll
  for (int i = 0; i < 2; ++i) {
    int row = m0 + ty + 16 * i;
    #pragma unroll
    for (int j = 0; j < 4; ++j) {
      int n = n0 + tx + 16 * j;
      float v = acc[i][j] * wscale;
      int y = n / 48, x = n % 48;
      int ppos = (y + 1) * 50 + (x + 1);
      if (mat < 2) {
        padC_cf[(u64)mat * (NC * NPIXP) + row * NPIXP + ppos] = v;
      } else {
        padS_cf[(u64)(mat - 2) * (NC * NPIXP) + row * NPIXP + ppos] = v;
        padS_cl[(u64)(mat - 2) * (NPIX * NC) + ppos * NC + row] = v;
      }
    }
  }
}

// ---------------- patch norms: rknorm = 1/||ker(ps)|| ----------------
__global__ void knorm_kernel(const float* __restrict__ padS_cl, float* __restrict__ rknorm) {
  int ps = blockIdx.x, b = blockIdx.y;
  int ys = ps / 48, xs = ps % 48;
  const float* S = padS_cl + (u64)b * (NPIX * NC);
  int ch = threadIdx.x;
  double acc = 0.0;
  #pragma unroll
  for (int dy = 0; dy < 3; ++dy)
    #pragma unroll
    for (int dx = 0; dx < 3; ++dx) {
      float v = S[((ys + dy) * 50 + xs + dx) * NC + ch];
      acc += (double)v * (double)v;
    }
  __shared__ double sd[256];
  int t = threadIdx.x;
  sd[t] = acc; __syncthreads();
  for (int st = 128; st > 0; st >>= 1) {
    if (t < st) sd[t] += sd[t + st];
    __syncthreads();
  }
  if (ch == 0) rknorm[b * HW + ps] = (float)(1.0 / sqrt(sd[0]));
}

// ---------------- pixel Gram: G[p][q] = sum_ch padC[ch][p]*padS[ch][q] ----------------
// 128x64 tile, 8x4 per thread, conflict-free LDS reads. grid(20,40), block(16,16).
__launch_bounds__(256)
__global__ void gram_gemm(const float* __restrict__ padC_cf, const float* __restrict__ padS_cf,
                          float* __restrict__ G, int b) {
  const float* A = padC_cf + (u64)b * (NC * NPIXP);
  const float* B = padS_cf + (u64)b * (NC * NPIXP);
  int p0 = blockIdx.x * 128, q0 = blockIdx.y * 64;
  __shared__ float As[16][128], Bs[16][64];
  int tx = threadIdx.x, ty = threadIdx.y;
  int tid = ty * 16 + tx;
  // A staging: 512 float4 -> 2/thread; B staging: 256 float4 -> 1/thread
  int ar0 = tid >> 5, ac0 = (tid & 31) << 2;
  int ar1 = (tid + 256) >> 5, ac1 = ac0;   // same column group, rows 0..7 then 8..15
  int br = tid >> 4, bc = (tid & 15) << 2;
  float acc[8][4] = {};
  for (int k0 = 0; k0 < 256; k0 += 16) {
    __syncthreads();
    *(float4*)&As[ar0][ac0] = *(const float4*)&A[(u64)(k0 + ar0) * NPIXP + p0 + ac0];
    *(float4*)&As[ar1][ac1] = *(const float4*)&A[(u64)(k0 + ar1) * NPIXP + p0 + ac1];
    *(float4*)&Bs[br][bc]   = *(const float4*)&B[(u64)(k0 + br) * NPIXP + q0 + bc];
    __syncthreads();
    #pragma unroll
    for (int kk = 0; kk < 16; ++kk) {
      float4 a0 = *(const float4*)&As[kk][ty * 8];      // 4 distinct addrs/wave: conflict-free
      float4 a1 = *(const float4*)&As[kk][ty * 8 + 4];
      float4 bv4 = *(const float4*)&Bs[kk][tx * 4];     // 16 addrs over 256B: 2-way (free)
      float av[8] = {a0.x, a0.y, a0.z, a0.w, a1.x, a1.y, a1.z, a1.w};
      float bv[4] = {bv4.x, bv4.y, bv4.z, bv4.w};
      #pragma unroll
      for (int i = 0; i < 8; ++i)
        #pragma unroll
        for (int j = 0; j < 4; ++j) acc[i][j] += av[i] * bv[j];
    }
  }
  #pragma unroll
  for (int i = 0; i < 8; ++i) {
    float4 v = make_float4(acc[i][0], acc[i][1], acc[i][2], acc[i][3]);
    *(float4*)&G[(u64)(p0 + ty * 8 + i) * NPIXP + q0 + tx * 4] = v;
  }
}

// ---------------- fused stencil + argmax ----------------
// grid(48 y, 48 ys), block 256. Per-block best per pc row, packed u64 atomicMax.
__launch_bounds__(256)
__global__ void scoremax_kernel(const float* __restrict__ G, const float* __restrict__ rknorm,
                                u64* __restrict__ rmax, int b) {
  int y = blockIdx.x, ys = blockIdx.y;
  __shared__ float Gt[3][50][50];
  __shared__ float sc[48][48];
  __shared__ float rkl[48];
  int tid = threadIdx.x;
  for (int t = tid; t < 7500; t += 256) {
    int dy = t / 2500, rem = t % 2500;
    int u = rem / 50, v = rem - u * 50;
    Gt[dy][u][v] = G[(u64)((y + dy) * 50 + u) * NPIXP + (ys + dy) * 50 + v];
  }
  if (tid < 48) rkl[tid] = rknorm[b * HW + ys * 48 + tid];
  __syncthreads();
  #pragma unroll
  for (int k = 0; k < 9; ++k) {
    int idx = tid + k * 256;
    int x = idx / 48, xs = idx - x * 48;
    float v = 0.0f;
    #pragma unroll
    for (int dy = 0; dy < 3; ++dy)
      #pragma unroll
      for (int dx = 0; dx < 3; ++dx)
        v += Gt[dy][x + dx][xs + dx];
    sc[x][xs] = v * rkl[xs];
  }
  __syncthreads();
  if (tid < 48) {
    float best = -1e30f; int bxs = 0;
    for (int xs = 0; xs < 48; ++xs) {
      float v = sc[tid][xs];
      if (v > best) { best = v; bxs = xs; }   // strict >: smallest xs on ties
    }
    int ps = ys * 48 + bxs;
    unsigned ub = __float_as_uint(best);
    unsigned enc = (ub & 0x80000000u) ? ~ub : (ub | 0x80000000u);
    u64 key = ((u64)enc << 32) | (u64)(2303 - ps);
    atomicMax(&rmax[(u64)b * HW + y * 48 + tid], key);
  }
}

// ---------------- reassemble: paste chosen patches + overlap normalize ----------------
__global__ void reassemble_kernel(const float* __restrict__ padS_cl, const u64* __restrict__ rmax,
                                  float* __restrict__ rF_cl) {
  int pix = blockIdx.x, b = blockIdx.y;
  int y = pix / 48, x = pix % 48;
  const u64* rm = rmax + (u64)b * HW;
  const float* S = padS_cl + (u64)b * (NPIX * NC);
  int ch = threadIdx.x;
  float sum = 0.0f;
  #pragma unroll
  for (int i = 0; i < 3; ++i)
    #pragma unroll
    for (int j = 0; j < 3; ++j) {
      int yn = y + 1 - i, xn = x + 1 - j;
      if (yn >= 0 && yn < 48 && xn >= 0 && xn < 48) {
        int ps = 2303 - (int)(unsigned)(rm[yn * 48 + xn] & 0xFFFFFFFFu);
        int ys = ps / 48, xs = ps % 48;
        sum += S[((ys + i) * 50 + xs + j) * NC + ch];
      }
    }
  float cy = (y == 0 || y == 47) ? 2.0f : 3.0f;
  float cx = (x == 0 || x == 47) ? 2.0f : 3.0f;
  rF_cl[(u64)b * (HW * NC) + pix * NC + ch] = sum / (cy * cx);
}

// ---------------- coloring: out = sqrt(s)*Yf*rF + mean_s ----------------
__launch_bounds__(256)
__global__ void coloring_kernel(const float* __restrict__ Yf, const double* __restrict__ snorm,
                                const double* __restrict__ mean, const float* __restrict__ rF_cl,
                                float* __restrict__ out) {
  int b = blockIdx.z;
  const float* A = Yf + (2 + b) * MATSZ;
  const float* Bp = rF_cl + (u64)b * (HW * NC);
  const double* mn = mean + (2 + b) * NC;
  float cscale = (float)sqrt(snorm[2 + b]);
  int m0 = blockIdx.y * 32, n0 = blockIdx.x * 64;
  __shared__ float As[32][33];
  __shared__ float Bs[32][65];
  int tx = threadIdx.x, ty = threadIdx.y;
  int tid = ty * 16 + tx;
  float acc[2][4] = {};
  for (int k0 = 0; k0 < 256; k0 += 32) {
    __syncthreads();
    #pragma unroll
    for (int l = 0; l < 4; ++l) {
      int idx = tid + l * 256;
      int r = idx >> 5, cc = idx & 31;
      As[r][cc] = A[(m0 + r) * NC + k0 + cc];
    }
    #pragma unroll
    for (int l = 0; l < 8; ++l) {
      int idx = tid + l * 256;
      int kk = idx & 31, nn = idx >> 5;
      Bs[kk][nn] = Bp[(u64)(n0 + nn) * NC + k0 + kk];
    }
    __syncthreads();
    #pragma unroll
    for (int kk = 0; kk < 32; ++kk) {
      float a0 = As[ty][kk], a1 = As[ty + 16][kk];
      float b0 = Bs[kk][tx], b1 = Bs[kk][tx + 16], b2 = Bs[kk][tx + 32], b3 = Bs[kk][tx + 48];
      acc[0][0] += a0 * b0; acc[0][1] += a0 * b1; acc[0][2] += a0 * b2; acc[0][3] += a0 * b3;
      acc[1][0] += a1 * b0; acc[1][1] += a1 * b1; acc[1][2] += a1 * b2; acc[1][3] += a1 * b3;
    }
  }
  #pragma unroll
  for (int i = 0; i < 2; ++i) {
    int row = m0 + ty + 16 * i;
    float madd = (float)mn[row];
    #pragma unroll
    for (int j = 0; j < 4; ++j) {
      int n = n0 + tx + 16 * j;
      out[(u64)b * (NC * HW) + row * HW + n] = acc[i][j] * cscale + madd;
    }
  }
}

// ---------------- host ----------------
extern "C" void kernel_launch(void* const* d_in, const int* in_sizes, int n_in,
                              void* d_out, int out_size, void* d_ws, size_t ws_size,
                              hipStream_t stream) {
  const float* c = (const float*)d_in[0];
  const float* s = (const float*)d_in[1];
  float* out = (float*)d_out;

  char* ws = (char*)d_ws;
  size_t off = 0;
  auto alloc = [&](size_t bytes) {
    void* p = ws + off;
    off = (off + bytes + 255) & ~(size_t)255;
    return p;
  };
  double* mean   = (double*)alloc(4 * NC * sizeof(double));
  float* cov     = (float*)alloc((size_t)4 * MATSZ * sizeof(float));
  float* covp    = (float*)alloc((size_t)4 * NSLAB * MATSZ * sizeof(float));
  float* Ya      = (float*)alloc((size_t)4 * MATSZ * sizeof(float));
  float* Yb      = (float*)alloc((size_t)4 * MATSZ * sizeof(float));
  float* Za      = (float*)alloc((size_t)4 * MATSZ * sizeof(float));
  float* Zb      = (float*)alloc((size_t)4 * MATSZ * sizeof(float));
  float* T       = (float*)alloc((size_t)4 * MATSZ * sizeof(float));
  // pads: three consecutive allocs, all sizes multiples of 256B -> one memset
  float* padC_cf = (float*)alloc((size_t)2 * NC * NPIXP * sizeof(float));
  float* padS_cf = (float*)alloc((size_t)2 * NC * NPIXP * sizeof(float));
  float* padS_cl = (float*)alloc((size_t)2 * NPIX * NC * sizeof(float));
  float* rknorm  = (float*)alloc((size_t)2 * HW * sizeof(float));
  float* rF_cl   = (float*)alloc((size_t)2 * HW * NC * sizeof(float));
  float* G       = (float*)alloc((size_t)NPIXP * NPIXP * sizeof(float)); // per-batch Gram
  // rmax (mult of 256B) + snorm: consecutive -> one memset
  u64*   rmax    = (u64*)alloc((size_t)2 * HW * sizeof(u64));
  double* snorm  = (double*)alloc(4 * sizeof(double));

  size_t padBytes = (size_t)(2 * NC * NPIXP + 2 * NC * NPIXP + 2 * NPIX * NC) * sizeof(float);
  hipMemsetAsync(padC_cf, 0, padBytes, stream);
  hipMemsetAsync(rmax, 0, (size_t)2 * HW * sizeof(u64) + 4 * sizeof(double), stream);

  mean_kernel<<<dim3(256, 4), 64, 0, stream>>>(c, s, mean);
  cov_part<<<dim3(4, 4, 4 * NSLAB), dim3(16, 16), 0, stream>>>(c, s, covp);
  cov_reduce<<<dim3(256, 4), 256, 0, stream>>>(covp, mean, cov, snorm);
  ns_init<<<dim3(256, 4), 256, 0, stream>>>(cov, snorm, Ya, Za);

  float *Yc = Ya, *Zc = Za, *Yn = Yb, *Zn = Zb;
  for (int it = 0; it < NS_ITERS; ++it) {
    ns_gemm_T<<<dim3(8, 8, 4), dim3(16, 16), 0, stream>>>(Zc, Yc, T);
    ns_gemm_YZ<<<dim3(8, 8, 8), dim3(16, 16), 0, stream>>>(Yc, Zc, T, Yn, Zn);
    float* t1 = Yc; Yc = Yn; Yn = t1;
    float* t2 = Zc; Zc = Zn; Zn = t2;
  }

  whiten_kernel<<<dim3(36, 8, 4), dim3(16, 16), 0, stream>>>(c, s, Zc, snorm, mean,
                                                             padC_cf, padS_cf, padS_cl);
  knorm_kernel<<<dim3(2304, 2), 256, 0, stream>>>(padS_cl, rknorm);

  for (int b = 0; b < 2; ++b) {
    gram_gemm<<<dim3(20, 40), dim3(16, 16), 0, stream>>>(padC_cf, padS_cf, G, b);
    scoremax_kernel<<<dim3(48, 48), 256, 0, stream>>>(G, rknorm, rmax, b);
  }

  reassemble_kernel<<<dim3(2304, 2), 256, 0, stream>>>(padS_cl, rmax, rF_cl);
  coloring_kernel<<<dim3(36, 8, 2), dim3(16, 16), 0, stream>>>(Yc, snorm, mean, rF_cl, out);
}